// Round 4
// baseline (436.082 us; speedup 1.0000x reference)
//
#include <hip/hip_runtime.h>
#include <hip/hip_bf16.h>
#include <math.h>

#define B_  16
#define C_  256
#define T_  4096
#define K_  5

typedef __attribute__((ext_vector_type(4))) float floatx4;
typedef __attribute__((ext_vector_type(8))) short short8;

// ALL tensors f32. CORRECTNESS CONTRACT (verified R7, absmax 0.03125):
//  - offset conv MUST be bit-exact vs the numpy golden: per-tap sequential
//    channel sums (c ascending 0..255), separate rounded mul+add (no FMA),
//    taps combined ((d0+d1)+d2), bias last, then pos = f32(t+k-2)+off in one
//    add. Exact-integer pos => both weights 0 (the discontinuity events).
//  - phase-B samples are raw f32 x values: staging them through LDS is
//    bit-preserving; pc==pf => both weights exactly 0 so the paired read's
//    second word is never used in that case. Out-of-window lanes fall back
//    to the identical global word.
//  - modulator conv / sigmoid are continuous: any precision/order OK.
//  - k3 may use bf16 MFMA (measured absmax 0.031 << thresholds).

// ---------------- ws layout (bytes) — total 232448 ----------------
// 0       wk1   f32 [3][256][10]   30720   (tap-major; f 0..4 offset, 5..9 mod)
// 30720   diagw f32 [256][5]       5120
// 35840   w_r   bf16 [3][128][256] 196608  (rp1_w repacked for k3 LDS staging)

__global__ __launch_bounds__(256) void k0_setup(
    const float* __restrict__ ow, const float* __restrict__ mw,
    const float* __restrict__ wt, const float* __restrict__ r1w,
    float* __restrict__ wk1, float* __restrict__ diagw,
    __hip_bfloat16* __restrict__ w_r)
{
    int idx = blockIdx.x * 256 + threadIdx.x;
    if (idx < 98304) {
        // rp1_w[(o*256+c)*3+d] -> w_r[(d*128+o)*256+c]
        int o = idx / 768; int rem = idx - o * 768; int c = rem / 3; int d = rem - c * 3;
        w_r[(size_t)(d * 128 + o) * 256 + c] = __float2bfloat16(r1w[idx]);
    }
    if (idx < 7680) {
        int d = idx / 2560; int rem = idx - d * 2560; int c = rem / 10; int f = rem - c * 10;
        wk1[idx] = (f < 5) ? ow[(f * C_ + c) * 3 + d] : mw[((f - 5) * C_ + c) * 3 + d];
    }
    if (idx < 1280) {
        int c = idx / 5; int k = idx - c * 5;
        diagw[idx] = wt[((size_t)c * C_ + c) * K_ + k];
    }
}

// phase-A helpers: 16-channel group load / process (strict order preserved)
#define LOADG(BUF, GG) do { \
    _Pragma("unroll") \
    for (int i_ = 0; i_ < 16; ++i_) \
        BUF[i_] = xp[(size_t)((GG) * 16 + i_) * T_]; \
} while (0)

#define PROCG(BUF, GG) do { \
    _Pragma("unroll") \
    for (int i_ = 0; i_ < 16; ++i_) { \
        const float v_ = inb ? BUF[i_] : 0.f; \
        const float* wr_ = wbase + ((GG) * 16 + i_) * 10; \
        { \
            _Pragma("clang fp contract(off)") \
            float q0 = wr_[0] * v_; so0 = so0 + q0; \
            float q1 = wr_[1] * v_; so1 = so1 + q1; \
            float q2 = wr_[2] * v_; so2 = so2 + q2; \
            float q3 = wr_[3] * v_; so3 = so3 + q3; \
            float q4 = wr_[4] * v_; so4 = so4 + q4; \
        } \
        am0 = fmaf(wr_[5], v_, am0); \
        am1 = fmaf(wr_[6], v_, am1); \
        am2 = fmaf(wr_[7], v_, am2); \
        am3 = fmaf(wr_[8], v_, am3); \
        am4 = fmaf(wr_[9], v_, am4); \
    } \
} while (0)

// K12 v5: 64-t tile, 256 threads, grid (64,16) = 1024 blocks.
// LDS 94.7 KB -> 1 block/CU (4 waves). Wave 3 stages x[t0-8..t0+71] (f32,
// all 256 c) into LDS concurrently with phase A (waves 0-2, tap-split conv,
// 3-buffer prefetch; their global reads L2-hit behind wave 3's stream).
// Phase B gathers from LDS (paired pf/pf+1 reads); rare out-of-window lanes
// take an exec-masked exact global fallback.
__global__ __launch_bounds__(256) void k12_fused(
    const float* __restrict__ x,
    const float* __restrict__ wk1,
    const float* __restrict__ ob, const float* __restrict__ mb,
    const float* __restrict__ diagw,
    float* __restrict__ dout)
{
    __shared__ __align__(16) float sx[256 * 80 + 4];   // 81936 B, rows [c][80]
    __shared__ float staps[3][K_][64];
    __shared__ float smod[3][K_][64];
    __shared__ int   spf[K_][64];
    __shared__ int   spc[K_][64];
    __shared__ float swa[K_][64];
    __shared__ float swb[K_][64];
    const int t0  = blockIdx.x * 64;
    const int b   = blockIdx.y;
    const int tid = threadIdx.x;
    const int tl  = tid & 63;
    const int wv  = tid >> 6;
    const int t   = t0 + tl;

    if (wv < 3) {
        const int wvu = __builtin_amdgcn_readfirstlane(wv);
        const int dd  = wvu - 1;                       // tap offset -1/0/+1
        const bool inb = ((unsigned)(t + dd) < (unsigned)T_);
        const float* xp = x + (size_t)b * C_ * T_ + t + (inb ? dd : 0);
        const float* wbase = wk1 + wvu * 2560;         // wave-uniform -> s_load
        float so0=0.f, so1=0.f, so2=0.f, so3=0.f, so4=0.f;   // strict chains
        float am0=0.f, am1=0.f, am2=0.f, am3=0.f, am4=0.f;   // mod partials
        float pA[16], pB[16], pC[16];
        LOADG(pA, 0); LOADG(pB, 1); LOADG(pC, 2);
#pragma unroll
        for (int g = 0; g < 16; g += 3) {
            PROCG(pA, g);
            if (g + 3 < 16) LOADG(pA, g + 3);
            if (g + 1 < 16) { PROCG(pB, g + 1); if (g + 4 < 16) LOADG(pB, g + 4); }
            if (g + 2 < 16) { PROCG(pC, g + 2); if (g + 5 < 16) LOADG(pC, g + 5); }
        }
        staps[wvu][0][tl] = so0; staps[wvu][1][tl] = so1; staps[wvu][2][tl] = so2;
        staps[wvu][3][tl] = so3; staps[wvu][4][tl] = so4;
        smod[wvu][0][tl]  = am0; smod[wvu][1][tl]  = am1; smod[wvu][2][tl]  = am2;
        smod[wvu][3][tl]  = am3; smod[wvu][4][tl]  = am4;
    } else {
        // ---- wave 3: stage x window [t0-8, t0+72) for all 256 c -> sx ----
        const float* xb = x + (size_t)b * C_ * T_;
        if (t0 >= 8 && t0 + 72 <= T_) {
            const float* src = xb + (t0 - 8);
            int c = tl / 20, q = tl - (tl / 20) * 20;   // float4 index (c,q)
            for (int it = 0; it < 80; ++it) {
                *(float4*)&sx[c * 80 + q * 4] =
                    *(const float4*)(src + (size_t)c * T_ + q * 4);
                q += 4; c += 3;
                if (q >= 20) { q -= 20; c += 1; }
            }
        } else {
            int c = 0, col = tl;
            for (int it = 0; it < 320; ++it) {
                int g = t0 - 8 + col;
                sx[c * 80 + col] = ((unsigned)g < (unsigned)T_)
                                 ? xb[(size_t)c * T_ + g] : 0.f;
                col += 64;
                if (col >= 80) { col -= 80; c += 1; }
            }
        }
    }
    __syncthreads();

    if (tid < 64) {
#pragma clang fp contract(off)
#pragma unroll
        for (int k = 0; k < K_; ++k) {
            float offv = ((staps[0][k][tl] + staps[1][k][tl]) + staps[2][k][tl]) + ob[k];
            float modv = ((smod[0][k][tl] + smod[1][k][tl]) + smod[2][k][tl]) + mb[k];
            float sig  = 1.f / (1.f + expf(-modv));
            float pos  = (float)(t + k - 2) + offv;   // single f32 add
            pos = fminf(fmaxf(pos, 0.f), 4095.f);
            float pf = floorf(pos), pc = ceilf(pos);
            spf[k][tl] = (int)pf;
            spc[k][tl] = (int)pc;
            swa[k][tl] = (pc - pos) * sig;
            swb[k][tl] = (pos - pf) * sig;
        }
    }
    __syncthreads();

    // ---- phase B: deform gather from LDS; thread (cg, tl): c in [cg*64, +64) ----
    const int cgU = __builtin_amdgcn_readfirstlane(wv);   // wave-uniform
    int   pfk[K_], pck[K_], ibase[K_];
    float ak[K_], bk[K_];
    bool  ow_[K_];
    bool  outl = false;
#pragma unroll
    for (int k = 0; k < K_; ++k) {
        pfk[k] = spf[k][tl]; pck[k] = spc[k][tl];
        ak[k]  = swa[k][tl]; bk[k]  = swb[k][tl];
        int xf = pfk[k] - (t0 - 8);
        int xc = pck[k] - (t0 - 8);
        ow_[k] = ((unsigned)xf >= 80u) | ((unsigned)xc >= 80u);
        outl  |= ow_[k];
        ibase[k] = ow_[k] ? 0 : xf;     // clamped base; pc in {pf, pf+1}
    }
    const bool anyout = __any(outl);
    const float* lx   = &sx[cgU * 64 * 80];
    const float* dwp  = diagw + cgU * 320;
    float*       dp   = dout + (size_t)(b * C_ + cgU * 64) * T_ + t;
    const float* xrow0 = x + (size_t)(b * C_ + cgU * 64) * T_;

#pragma unroll 4
    for (int j = 0; j < 64; ++j) {
        float vf[K_], vc[K_];
#pragma unroll
        for (int k = 0; k < K_; ++k) {
            vf[k] = lx[j * 80 + ibase[k]];        // paired (pf, pf+1) read;
            vc[k] = lx[j * 80 + ibase[k] + 1];    // pc==pf => bk==0, unused
        }
        if (anyout) {                              // rare exact fallback
            const float* xrow = xrow0 + (size_t)j * T_;
#pragma unroll
            for (int k = 0; k < K_; ++k)
                if (ow_[k]) { vf[k] = xrow[pfk[k]]; vc[k] = xrow[pck[k]]; }
        }
        float a0 = 0.f;
#pragma unroll
        for (int k = 0; k < K_; ++k)
            a0 += dwp[j * 5 + k] * (vf[k] * ak[k] + vc[k] * bk[k]);
        dp[(size_t)j * T_] = a0;
    }
}

// K3 v4: v2 structure + T14 reg-staging split: global loads for chunk ch+1
// are issued right after the stage barrier and consumed at the next iter's
// ds_write, so HBM latency hides under the MFMA cluster. Layout unchanged.
// LDS 36 KB -> 4 blocks/CU.
__global__ __launch_bounds__(256) void k3_rp(
    const float* __restrict__ ddef,              // f32 deformed [b][c][t] (d_out)
    const __hip_bfloat16* __restrict__ w_r,      // bf16 [3][128][256]
    const float* __restrict__ rp1b, const float* __restrict__ rp2w,
    const float* __restrict__ rp2b,
    float* __restrict__ rec)
{
    __shared__ __align__(16) short lw[3 * 128 * 40];  // [d][o][c stride 40] 30720 B
    __shared__ __align__(16) short ld[66 * 40];       // [j 66][c stride 40]   5280 B
    const int t0 = blockIdx.x * 64;
    const int b  = blockIdx.y;
    const int tid  = threadIdx.x;
    const int lane = tid & 63;
    const int w    = tid >> 6;      // wave id = n-tile
    const int qd   = lane >> 4;
    const int ln   = lane & 15;
    const short* wsrc = (const short*)w_r;

    floatx4 acc[8];
#pragma unroll
    for (int m = 0; m < 8; ++m) acc[m] = (floatx4){0.f, 0.f, 0.f, 0.f};

    // per-thread staging coordinates (static)
    int wo[6], wd[6], wc8[6];
#pragma unroll
    for (int i = 0; i < 6; ++i) {
        int f = tid + i * 256;      // < 1536
        wc8[i] = (f & 3) * 8;
        wo[i]  = (f >> 2) & 127;
        wd[i]  = f >> 9;
    }
    int sc[9], sj[9];
#pragma unroll
    for (int i = 0; i < 9; ++i) {
        int f = tid + i * 256;
        sc[i] = f / 66;
        sj[i] = f - sc[i] * 66;
    }

    int4  wreg[6];
    float dreg[9];
#define K3_LOADW(CH) do { \
    _Pragma("unroll") \
    for (int i_ = 0; i_ < 6; ++i_) \
        wreg[i_] = *(const int4*)(wsrc + (size_t)(wd[i_] * 128 + wo[i_]) * 256 \
                                  + (CH) * 32 + wc8[i_]); \
} while (0)
#define K3_LOADD(CH) do { \
    _Pragma("unroll") \
    for (int i_ = 0; i_ < 9; ++i_) { \
        if (tid + i_ * 256 < 2112) { \
            int g_ = t0 - 1 + sj[i_]; \
            dreg[i_] = ((unsigned)g_ < (unsigned)T_) \
                     ? ddef[(size_t)(b * C_ + (CH) * 32 + sc[i_]) * T_ + g_] : 0.f; \
        } \
    } \
} while (0)

    K3_LOADW(0); K3_LOADD(0);

    for (int ch = 0; ch < 8; ++ch) {
        // write staged regs to LDS (previous MFMA done per trailing barrier)
#pragma unroll
        for (int i = 0; i < 6; ++i)
            *(int4*)&lw[(wd[i] * 128 + wo[i]) * 40 + wc8[i]] = wreg[i];
#pragma unroll
        for (int i = 0; i < 9; ++i) {
            if (tid + i * 256 < 2112) {
                __hip_bfloat16 h = __float2bfloat16(dreg[i]);
                ld[sj[i] * 40 + sc[i]] = *(short*)&h;
            }
        }
        __syncthreads();
        if (ch < 7) { K3_LOADW(ch + 1); K3_LOADD(ch + 1); }   // overlap w/ MFMA
#pragma unroll
        for (int d = 0; d < 3; ++d) {
            short8 bf = *(const short8*)&ld[(w * 16 + ln + d) * 40 + qd * 8];
#pragma unroll
            for (int m = 0; m < 8; ++m) {
                short8 af = *(const short8*)&lw[(d * 128 + m * 16 + ln) * 40 + qd * 8];
                acc[m] = __builtin_amdgcn_mfma_f32_16x16x32_bf16(af, bf, acc[m], 0, 0, 0);
            }
        }
        __syncthreads();
    }

    // epilogue (C/D layout: col=ln -> t, row=qd*4+reg -> o)
    float rv = 0.f;
#pragma unroll
    for (int m = 0; m < 8; ++m)
#pragma unroll
        for (int r = 0; r < 4; ++r) {
            int o = m * 16 + qd * 4 + r;
            float h = acc[m][r] + rp1b[o];
            h = h > 0.f ? h : 0.f;
            rv += rp2w[o] * h;
        }
    rv += __shfl_xor(rv, 16);
    rv += __shfl_xor(rv, 32);
    if (qd == 0)
        rec[b * T_ + t0 + w * 16 + ln] = rv + rp2b[0];
}

extern "C" void kernel_launch(void* const* d_in, const int* in_sizes, int n_in,
                              void* d_out, int out_size, void* d_ws, size_t ws_size,
                              hipStream_t stream) {
    const float* x   = (const float*)d_in[0];
    const float* ow  = (const float*)d_in[1];
    const float* ob  = (const float*)d_in[2];
    const float* mw  = (const float*)d_in[3];
    const float* mb  = (const float*)d_in[4];
    const float* wt  = (const float*)d_in[5];
    const float* r1w = (const float*)d_in[6];
    const float* r1b = (const float*)d_in[7];
    const float* r2w = (const float*)d_in[8];
    const float* r2b = (const float*)d_in[9];

    char* ws = (char*)d_ws;
    float*          wk1   = (float*)(ws + 0);
    float*          diagw = (float*)(ws + 30720);
    __hip_bfloat16* w_r   = (__hip_bfloat16*)(ws + 35840);

    float* dout = (float*)d_out;
    float* rec  = (float*)d_out + (size_t)B_ * C_ * T_;

    k0_setup<<<384, 256, 0, stream>>>(ow, mw, wt, r1w, wk1, diagw, w_r);
    k12_fused<<<dim3(T_ / 64, B_), 256, 0, stream>>>(x, wk1, ob, mb, diagw, dout);
    k3_rp<<<dim3(T_ / 64, B_), 256, 0, stream>>>(dout, w_r, r1b, r2w, r2b, rec);
}

// Round 5
// 252.135 us; speedup vs baseline: 1.7296x; 1.7296x over previous
//
#include <hip/hip_runtime.h>
#include <hip/hip_bf16.h>
#include <math.h>

#define B_  16
#define C_  256
#define T_  4096
#define K_  5

typedef __attribute__((ext_vector_type(4))) float floatx4;
typedef __attribute__((ext_vector_type(8))) short short8;

// ALL tensors f32. CORRECTNESS CONTRACT (verified, absmax 0.03125):
//  - offset conv MUST be bit-exact vs the numpy golden: per-tap sequential
//    channel sums (c ascending 0..255), separate rounded mul+add (no FMA),
//    taps combined ((d0+d1)+d2), bias last, then pos = f32(t+k-2)+off in one
//    add. Exact-integer pos => both weights 0 (the discontinuity events).
//    Tap-split across waves preserves bit-exactness (each (d,f) chain keeps
//    its full-length c-order).
//  - sampled values are raw f32 x words whether read via LDS or global;
//    pc==pf => both weights exactly 0 so the paired (pf,pf+1) read's second
//    word is never used in that case. pc==pf+1 whenever any weight != 0.
//  - modulator conv / sigmoid are continuous: any precision/order OK.
//  - k3 may use bf16 MFMA (measured absmax 0.031 << thresholds).

// ---------------- ws layout (bytes) ----------------
// 0        wk1   f32 [3][256][10]   30720  (tap-major; f 0..4 offset, 5..9 mod)
// 30720    diagw f32 [256][5]       5120
// 35840    w_r   bf16 [3][128][256] 196608 (rp1_w repacked for k3 LDS staging)
// 232448   wpf   s16 [B][5][T]      655360   (k1->k2, only if ws_size allows)
// 887808   wwa   f32 [B][5][T]      1310720
// 2198528  wwb   f32 [B][5][T]      1310720
// total with pos arrays: 3509248
#define WS_NEED 3509248

__global__ __launch_bounds__(256) void k0_setup(
    const float* __restrict__ ow, const float* __restrict__ mw,
    const float* __restrict__ wt, const float* __restrict__ r1w,
    float* __restrict__ wk1, float* __restrict__ diagw,
    __hip_bfloat16* __restrict__ w_r)
{
    int idx = blockIdx.x * 256 + threadIdx.x;
    if (idx < 98304) {
        // rp1_w[(o*256+c)*3+d] -> w_r[(d*128+o)*256+c]
        int o = idx / 768; int rem = idx - o * 768; int c = rem / 3; int d = rem - c * 3;
        w_r[(size_t)(d * 128 + o) * 256 + c] = __float2bfloat16(r1w[idx]);
    }
    if (idx < 7680) {
        int d = idx / 2560; int rem = idx - d * 2560; int c = rem / 10; int f = rem - c * 10;
        wk1[idx] = (f < 5) ? ow[(f * C_ + c) * 3 + d] : mw[((f - 5) * C_ + c) * 3 + d];
    }
    if (idx < 1280) {
        int c = idx / 5; int k = idx - c * 5;
        diagw[idx] = wt[((size_t)c * C_ + c) * K_ + k];
    }
}

// phase-A helpers: 16-channel group load / process (strict order preserved)
#define LOADG(BUF, GG) do { \
    _Pragma("unroll") \
    for (int i_ = 0; i_ < 16; ++i_) \
        BUF[i_] = xp[(size_t)((GG) * 16 + i_) * T_]; \
} while (0)

#define PROCG(BUF, GG) do { \
    _Pragma("unroll") \
    for (int i_ = 0; i_ < 16; ++i_) { \
        const float v_ = inb ? BUF[i_] : 0.f; \
        const float* wr_ = wbase + ((GG) * 16 + i_) * 10; \
        { \
            _Pragma("clang fp contract(off)") \
            float q0 = wr_[0] * v_; so0 = so0 + q0; \
            float q1 = wr_[1] * v_; so1 = so1 + q1; \
            float q2 = wr_[2] * v_; so2 = so2 + q2; \
            float q3 = wr_[3] * v_; so3 = so3 + q3; \
            float q4 = wr_[4] * v_; so4 = so4 + q4; \
        } \
        am0 = fmaf(wr_[5], v_, am0); \
        am1 = fmaf(wr_[6], v_, am1); \
        am2 = fmaf(wr_[7], v_, am2); \
        am3 = fmaf(wr_[8], v_, am3); \
        am4 = fmaf(wr_[9], v_, am4); \
    } \
} while (0)

// phase-A body shared by k1_off and the fallback fused kernel.
#define PHASE_A_BODY(STAPS, SMOD) do { \
    const int wvu = __builtin_amdgcn_readfirstlane(wv); \
    const int dd  = wvu - 1; \
    const bool inb = ((unsigned)(t + dd) < (unsigned)T_); \
    const float* xp = x + (size_t)b * C_ * T_ + t + (inb ? dd : 0); \
    const float* wbase = wk1 + wvu * 2560; \
    float so0=0.f, so1=0.f, so2=0.f, so3=0.f, so4=0.f; \
    float am0=0.f, am1=0.f, am2=0.f, am3=0.f, am4=0.f; \
    float pA[16], pB[16], pC[16]; \
    LOADG(pA, 0); LOADG(pB, 1); LOADG(pC, 2); \
    _Pragma("unroll") \
    for (int g = 0; g < 16; g += 3) { \
        PROCG(pA, g); \
        if (g + 3 < 16) LOADG(pA, g + 3); \
        if (g + 1 < 16) { PROCG(pB, g + 1); if (g + 4 < 16) LOADG(pB, g + 4); } \
        if (g + 2 < 16) { PROCG(pC, g + 2); if (g + 5 < 16) LOADG(pC, g + 5); } \
    } \
    STAPS[wvu][0][tl] = so0; STAPS[wvu][1][tl] = so1; STAPS[wvu][2][tl] = so2; \
    STAPS[wvu][3][tl] = so3; STAPS[wvu][4][tl] = so4; \
    SMOD[wvu][0][tl]  = am0; SMOD[wvu][1][tl]  = am1; SMOD[wvu][2][tl]  = am2; \
    SMOD[wvu][3][tl]  = am3; SMOD[wvu][4][tl]  = am4; \
} while (0)

// K1: offsets-only kernel. 192 threads (3 tap-split conv waves), LDS 7.7 KB
// -> ~10 blocks/CU, 30 waves/CU: conv latency fully hidden by TLP.
__global__ __launch_bounds__(192) void k1_off(
    const float* __restrict__ x,
    const float* __restrict__ wk1,
    const float* __restrict__ ob, const float* __restrict__ mb,
    short* __restrict__ wpf, float* __restrict__ wwa, float* __restrict__ wwb)
{
    __shared__ float staps[3][K_][64];
    __shared__ float smod[3][K_][64];
    const int t0  = blockIdx.x * 64;
    const int b   = blockIdx.y;
    const int tid = threadIdx.x;
    const int tl  = tid & 63;
    const int wv  = tid >> 6;      // 0..2
    const int t   = t0 + tl;

    PHASE_A_BODY(staps, smod);
    __syncthreads();

    if (tid < 64) {
#pragma clang fp contract(off)
#pragma unroll
        for (int k = 0; k < K_; ++k) {
            float offv = ((staps[0][k][tl] + staps[1][k][tl]) + staps[2][k][tl]) + ob[k];
            float modv = ((smod[0][k][tl] + smod[1][k][tl]) + smod[2][k][tl]) + mb[k];
            float sig  = 1.f / (1.f + expf(-modv));
            float pos  = (float)(t + k - 2) + offv;   // single f32 add
            pos = fminf(fmaxf(pos, 0.f), 4095.f);
            float pf = floorf(pos), pc = ceilf(pos);
            wpf[(size_t)(b * 5 + k) * T_ + t] = (short)(int)pf;
            wwa[(size_t)(b * 5 + k) * T_ + t] = (pc - pos) * sig;
            wwb[(size_t)(b * 5 + k) * T_ + t] = (pos - pf) * sig;
        }
    }
}

// K2: deform gather. Tile = 64 c x 64 t, grid (64, 4, 16) = 4096 blocks,
// LDS 20.5 KB -> 7 blocks/CU (28 waves): gather reads hit LDS, latency
// hidden by TLP. Window [t0-8, t0+72); rare out-of-window lanes take an
// exec-masked exact global fallback (wave-uniform skip for 99.5% of waves).
__global__ __launch_bounds__(256) void k2_gather(
    const float* __restrict__ x,
    const float* __restrict__ diagw,
    const short* __restrict__ wpf, const float* __restrict__ wwa,
    const float* __restrict__ wwb,
    float* __restrict__ dout)
{
    __shared__ __align__(16) float sx[64 * 80 + 4];  // [c 64][col 80] + pad
    const int t0 = blockIdx.x * 64;
    const int cg = blockIdx.y;
    const int b  = blockIdx.z;
    const int c0 = cg * 64;
    const int tid = threadIdx.x;
    const int tl  = tid & 63;
    const int wv  = __builtin_amdgcn_readfirstlane(tid >> 6);
    const int t   = t0 + tl;

    const float* xb = x + (size_t)(b * C_ + c0) * T_;

    // ---- stage x[c0..c0+64)[t0-8..t0+72) -> sx (coalesced float4) ----
    if (t0 >= 8 && t0 + 72 <= T_) {
#pragma unroll
        for (int i = 0; i < 5; ++i) {
            int f = tid + i * 256;          // 0..1279
            int r = f / 20, q = f - r * 20;
            *(float4*)&sx[r * 80 + q * 4] =
                *(const float4*)(xb + (size_t)r * T_ + (t0 - 8) + q * 4);
        }
    } else {
#pragma unroll
        for (int i = 0; i < 5; ++i) {
            int f = tid + i * 256;
            int r = f / 20, q = f - r * 20;
#pragma unroll
            for (int e = 0; e < 4; ++e) {
                int g = t0 - 8 + q * 4 + e;
                sx[r * 80 + q * 4 + e] = ((unsigned)g < (unsigned)T_)
                                       ? xb[(size_t)r * T_ + g] : 0.f;
            }
        }
    }

    // ---- per-lane pos params (coalesced: consecutive t per lane) ----
    int pfg[K_], ib[K_];
    float ak[K_], bk[K_];
    bool ow_[K_];
    bool o = false;
#pragma unroll
    for (int k = 0; k < K_; ++k) {
        pfg[k] = (int)wpf[(size_t)(b * 5 + k) * T_ + t];
        ak[k]  = wwa[(size_t)(b * 5 + k) * T_ + t];
        bk[k]  = wwb[(size_t)(b * 5 + k) * T_ + t];
        ib[k]  = pfg[k] - (t0 - 8);
        ow_[k] = ((unsigned)ib[k] > 78u);   // ib+1 must be < 80
        o |= ow_[k];
        if (ow_[k]) ib[k] = 0;
    }
    const bool anyout = __any(o);
    __syncthreads();

    // ---- 16 channels per thread: c = c0 + wv*16 + j ----
    float* dp = dout + (size_t)(b * C_ + c0) * T_ + t;
#pragma unroll 4
    for (int j = 0; j < 16; ++j) {
        const int cl = wv * 16 + j;          // wave-uniform
        const float* lx = &sx[cl * 80];
        float vf[K_], vc[K_];
#pragma unroll
        for (int k = 0; k < K_; ++k) {
            vf[k] = lx[ib[k]];               // paired (pf, pf+1);
            vc[k] = lx[ib[k] + 1];           // pc==pf => bk==0, unused
        }
        if (anyout) {                        // rare exact fallback
            const float* xr = xb + (size_t)cl * T_;
#pragma unroll
            for (int k = 0; k < K_; ++k)
                if (ow_[k]) {
                    int pi = pfg[k];
                    int ci = pi + 1 > 4095 ? 4095 : pi + 1;
                    vf[k] = xr[pi]; vc[k] = xr[ci];
                }
        }
        const float* dw = diagw + (c0 + cl) * 5;   // wave-uniform -> s_load
        float acc = 0.f;
#pragma unroll
        for (int k = 0; k < K_; ++k)
            acc += dw[k] * (vf[k] * ak[k] + vc[k] * bk[k]);
        dp[(size_t)cl * T_] = acc;
    }
}

// Fallback fused kernel (R3-verified, 134.5 us): used only if ws_size is too
// small for the k1/k2 pos arrays. Phase A tap-split + phase B global gather.
__global__ __launch_bounds__(256) void k12_fallback(
    const float* __restrict__ x,
    const float* __restrict__ wk1,
    const float* __restrict__ ob, const float* __restrict__ mb,
    const float* __restrict__ diagw,
    float* __restrict__ dout)
{
    __shared__ float staps[3][K_][64];
    __shared__ float smod[3][K_][64];
    __shared__ int   spf[K_][64];
    __shared__ int   spc[K_][64];
    __shared__ float swa[K_][64];
    __shared__ float swb[K_][64];
    const int t0  = blockIdx.x * 64;
    const int b   = blockIdx.y;
    const int tid = threadIdx.x;
    const int tl  = tid & 63;
    const int wv  = tid >> 6;
    const int t   = t0 + tl;

    if (wv < 3) {
        PHASE_A_BODY(staps, smod);
    }
    __syncthreads();

    if (tid < 64) {
#pragma clang fp contract(off)
#pragma unroll
        for (int k = 0; k < K_; ++k) {
            float offv = ((staps[0][k][tl] + staps[1][k][tl]) + staps[2][k][tl]) + ob[k];
            float modv = ((smod[0][k][tl] + smod[1][k][tl]) + smod[2][k][tl]) + mb[k];
            float sig  = 1.f / (1.f + expf(-modv));
            float pos  = (float)(t + k - 2) + offv;
            pos = fminf(fmaxf(pos, 0.f), 4095.f);
            float pf = floorf(pos), pc = ceilf(pos);
            spf[k][tl] = (int)pf;
            spc[k][tl] = (int)pc;
            swa[k][tl] = (pc - pos) * sig;
            swb[k][tl] = (pos - pf) * sig;
        }
    }
    __syncthreads();

    const int cgU = __builtin_amdgcn_readfirstlane(wv);
    int   pfk[K_], pck[K_];
    float ak[K_], bk[K_];
#pragma unroll
    for (int k = 0; k < K_; ++k) {
        pfk[k] = spf[k][tl]; pck[k] = spc[k][tl];
        ak[k]  = swa[k][tl]; bk[k]  = swb[k][tl];
    }
    const float* xr  = x    + (size_t)(b * C_ + cgU * 64) * T_;
    float*       dp  = dout + (size_t)(b * C_ + cgU * 64) * T_ + t;
    const float* dwp = diagw + cgU * 320;
    float vfA[K_], vcA[K_], vfB[K_], vcB[K_];
#pragma unroll
    for (int k = 0; k < K_; ++k) {
        vfA[k] = xr[pfk[k]];              vcA[k] = xr[pck[k]];
        vfB[k] = xr[T_ + pfk[k]];         vcB[k] = xr[T_ + pck[k]];
    }
    for (int j = 0; j < 64; j += 2) {
        float nfA[K_], ncA[K_], nfB[K_], ncB[K_];
        if (j < 62) {
            const float* xa  = xr + (size_t)(j + 2) * T_;
            const float* xb2 = xr + (size_t)(j + 3) * T_;
#pragma unroll
            for (int k = 0; k < K_; ++k) {
                nfA[k] = xa[pfk[k]];  ncA[k] = xa[pck[k]];
                nfB[k] = xb2[pfk[k]]; ncB[k] = xb2[pck[k]];
            }
        }
        float a0 = 0.f, a1 = 0.f;
#pragma unroll
        for (int k = 0; k < K_; ++k) {
            a0 += dwp[j * 5 + k]       * (vfA[k] * ak[k] + vcA[k] * bk[k]);
            a1 += dwp[(j + 1) * 5 + k] * (vfB[k] * ak[k] + vcB[k] * bk[k]);
        }
        dp[(size_t)j * T_]       = a0;
        dp[(size_t)(j + 1) * T_] = a1;
        if (j < 62) {
#pragma unroll
            for (int k = 0; k < K_; ++k) {
                vfA[k] = nfA[k]; vcA[k] = ncA[k];
                vfB[k] = nfB[k]; vcB[k] = ncB[k];
            }
        }
    }
}

// K3 v2 (R0/R3-verified, ~50 us): 64-t tile, grid (64,16), LDS 36 KB ->
// 4 blocks/CU (16 waves/CU). Wave w = n-tile (16 t); 8 m-tiles of 16 o;
// K = 256c x 3taps. W staged in LDS per chunk (L2-resident source).
__global__ __launch_bounds__(256) void k3_rp(
    const float* __restrict__ ddef,              // f32 deformed [b][c][t] (d_out)
    const __hip_bfloat16* __restrict__ w_r,      // bf16 [3][128][256]
    const float* __restrict__ rp1b, const float* __restrict__ rp2w,
    const float* __restrict__ rp2b,
    float* __restrict__ rec)
{
    __shared__ __align__(16) short lw[3 * 128 * 40];  // [d][o][c stride 40] 30720 B
    __shared__ __align__(16) short ld[66 * 40];       // [j 66][c stride 40]   5280 B
    const int t0 = blockIdx.x * 64;
    const int b  = blockIdx.y;
    const int tid  = threadIdx.x;
    const int lane = tid & 63;
    const int w    = tid >> 6;      // wave id = n-tile
    const int qd   = lane >> 4;
    const int ln   = lane & 15;

    floatx4 acc[8];
#pragma unroll
    for (int m = 0; m < 8; ++m) acc[m] = (floatx4){0.f, 0.f, 0.f, 0.f};

    for (int ch = 0; ch < 8; ++ch) {
        int c0 = ch * 32;
        __syncthreads();
        // stage W chunk [3][128][32], 16B copies (6 per thread)
        for (int f = tid; f < 1536; f += 256) {
            int c8 = (f & 3) * 8;
            int o  = (f >> 2) & 127;
            int d  = f >> 9;
            *(int4*)&lw[(d * 128 + o) * 40 + c8] =
                *(const int4*)((const short*)w_r + (size_t)(d * 128 + o) * 256 + c0 + c8);
        }
        // stage D chunk transposed: ld[j][c], j -> global t0-1+j
        for (int f = tid; f < 32 * 66; f += 256) {
            int c = f / 66;
            int j = f - c * 66;
            int g = t0 - 1 + j;
            float v = (g >= 0 && g < T_) ? ddef[(size_t)(b * C_ + c0 + c) * T_ + g] : 0.f;
            __hip_bfloat16 h = __float2bfloat16(v);
            ld[j * 40 + c] = *(short*)&h;
        }
        __syncthreads();
#pragma unroll
        for (int d = 0; d < 3; ++d) {
            short8 bf = *(const short8*)&ld[(w * 16 + ln + d) * 40 + qd * 8];
#pragma unroll
            for (int m = 0; m < 8; ++m) {
                short8 af = *(const short8*)&lw[(d * 128 + m * 16 + ln) * 40 + qd * 8];
                acc[m] = __builtin_amdgcn_mfma_f32_16x16x32_bf16(af, bf, acc[m], 0, 0, 0);
            }
        }
    }

    // epilogue (C/D layout: col=ln -> t, row=qd*4+reg -> o)
    float rv = 0.f;
#pragma unroll
    for (int m = 0; m < 8; ++m)
#pragma unroll
        for (int r = 0; r < 4; ++r) {
            int o = m * 16 + qd * 4 + r;
            float h = acc[m][r] + rp1b[o];
            h = h > 0.f ? h : 0.f;
            rv += rp2w[o] * h;
        }
    rv += __shfl_xor(rv, 16);
    rv += __shfl_xor(rv, 32);
    if (qd == 0)
        rec[b * T_ + t0 + w * 16 + ln] = rv + rp2b[0];
}

extern "C" void kernel_launch(void* const* d_in, const int* in_sizes, int n_in,
                              void* d_out, int out_size, void* d_ws, size_t ws_size,
                              hipStream_t stream) {
    const float* x   = (const float*)d_in[0];
    const float* ow  = (const float*)d_in[1];
    const float* ob  = (const float*)d_in[2];
    const float* mw  = (const float*)d_in[3];
    const float* mb  = (const float*)d_in[4];
    const float* wt  = (const float*)d_in[5];
    const float* r1w = (const float*)d_in[6];
    const float* r1b = (const float*)d_in[7];
    const float* r2w = (const float*)d_in[8];
    const float* r2b = (const float*)d_in[9];

    char* ws = (char*)d_ws;
    float*          wk1   = (float*)(ws + 0);
    float*          diagw = (float*)(ws + 30720);
    __hip_bfloat16* w_r   = (__hip_bfloat16*)(ws + 35840);
    short*          wpf   = (short*)(ws + 232448);
    float*          wwa   = (float*)(ws + 887808);
    float*          wwb   = (float*)(ws + 2198528);

    float* dout = (float*)d_out;
    float* rec  = (float*)d_out + (size_t)B_ * C_ * T_;

    k0_setup<<<384, 256, 0, stream>>>(ow, mw, wt, r1w, wk1, diagw, w_r);
    if (ws_size >= (size_t)WS_NEED) {
        k1_off<<<dim3(T_ / 64, B_), 192, 0, stream>>>(x, wk1, ob, mb, wpf, wwa, wwb);
        k2_gather<<<dim3(T_ / 64, 4, B_), 256, 0, stream>>>(x, diagw, wpf, wwa, wwb, dout);
    } else {
        k12_fallback<<<dim3(T_ / 64, B_), 256, 0, stream>>>(x, wk1, ob, mb, diagw, dout);
    }
    k3_rp<<<dim3(T_ / 64, B_), 256, 0, stream>>>(dout, w_r, r1b, r2w, r2b, rec);
}